// Round 3
// baseline (1016.884 us; speedup 1.0000x reference)
//
#include <hip/hip_runtime.h>
#include <math.h>

// B=1024, S=256, D=256 fp32.
// logp[b,s] = -0.5*(D*log2pi + logdet_s + ||L_s^{-1}(x_b-mu_s)||^2)
//
// ws: one 256x256 fp32 matrix M per s (64 MB). Lifecycle:
//   ridge -> M[128];  gram -> lower+diag = sigma
//   panel(kb): factor diag kb, write W=invD (fp32) OVER diag kb,
//              TRSM sub-panel: L blocks to lower AND L^T copies to upper (kb,i)
//   trail(kb): C(ti,tj) -= L_i L_j^T (reads upper copies, updates lower)
//   inv: per s, build invL blockwise; all lower+diag blocks overwritten with
//        PACKED uint32 = (bf16_hi<<16)|bf16_lo of invL (upper-in-diag zeros kept)
//   maha: y = invL*diff via mfma_f32_16x16x32_bf16 split-3; maha = colnorm(y)^2;
//         logdet = -2*sum log(invL_kk) read from packed diag.

#define LOG2PI_D 470.4965290007924f  // 256*log(2*pi)

typedef __attribute__((ext_vector_type(8))) short bf16x8;
typedef __attribute__((ext_vector_type(4))) float f32x4;

__device__ __forceinline__ unsigned bf16rtn(float f) {
  unsigned u = __float_as_uint(f);
  return (u + 0x7FFFu + ((u >> 16) & 1u)) >> 16;
}
__device__ __forceinline__ unsigned packhl(float v) {
  unsigned h = bf16rtn(v);
  float hf = __uint_as_float(h << 16);
  unsigned l = bf16rtn(v - hf);
  return (h << 16) | l;
}

__global__ __launch_bounds__(256) void k_ridge(const float* __restrict__ sp,
                                               float* __restrict__ L) {
  int s = blockIdx.x;
  const float4* p = (const float4*)(sp + (size_t)s * 65536);
  float acc = 0.f;
#pragma unroll 4
  for (int it = 0; it < 64; ++it) {
    float4 v = p[threadIdx.x + it * 256];
    acc += v.x * v.x + v.y * v.y + v.z * v.z + v.w * v.w;
  }
  for (int off = 32; off > 0; off >>= 1) acc += __shfl_down(acc, off, 64);
  __shared__ float red[4];
  if ((threadIdx.x & 63) == 0) red[threadIdx.x >> 6] = acc;
  __syncthreads();
  if (threadIdx.x == 0) {
    float t = red[0] + red[1] + red[2] + red[3];
    L[(size_t)s * 65536 + 128] = 0.01f * t / 256.0f;
  }
}

// Gram: C = sp^T sp (+ridge diag). 128x128 lower blocks only.
__global__ __launch_bounds__(256) void k_gram(const float* __restrict__ sp,
                                              float* __restrict__ L) {
  const int pi_[3] = {0, 1, 1};
  const int pj_[3] = {0, 0, 1};
  int p = blockIdx.x, s = blockIdx.y;
  int bi = pi_[p] * 128, bj = pj_[p] * 128;
  const float* A = sp + (size_t)s * 65536;
  float* C = L + (size_t)s * 65536;
  __shared__ float As[32][132];
  __shared__ float Bs[32][132];
  float acc[8][8] = {};
  int ty = threadIdx.x / 16, tx = threadIdx.x % 16;
  int lc4 = threadIdx.x % 32, lrb = threadIdx.x / 32;
  float ridge = C[128];
  for (int k0 = 0; k0 < 256; k0 += 32) {
    __syncthreads();
#pragma unroll
    for (int pass = 0; pass < 4; ++pass) {
      int r = lrb + pass * 8;
      *(float4*)&As[r][lc4 * 4] = *(const float4*)(A + (size_t)(k0 + r) * 256 + bi + lc4 * 4);
      *(float4*)&Bs[r][lc4 * 4] = *(const float4*)(A + (size_t)(k0 + r) * 256 + bj + lc4 * 4);
    }
    __syncthreads();
#pragma unroll
    for (int kk = 0; kk < 32; ++kk) {
      float a[8], b[8];
      *(float4*)&a[0] = *(float4*)&As[kk][ty * 8];
      *(float4*)&a[4] = *(float4*)&As[kk][ty * 8 + 4];
      *(float4*)&b[0] = *(float4*)&Bs[kk][tx * 8];
      *(float4*)&b[4] = *(float4*)&Bs[kk][tx * 8 + 4];
#pragma unroll
      for (int i = 0; i < 8; ++i)
#pragma unroll
        for (int j = 0; j < 8; ++j) acc[i][j] += a[i] * b[j];
    }
  }
#pragma unroll
  for (int i = 0; i < 8; ++i) {
    int d = bi + ty * 8 + i;
#pragma unroll
    for (int j = 0; j < 8; ++j) {
      int e = bj + tx * 8 + j;
      if (d == e) acc[i][j] += ridge;
    }
    *(float4*)(C + (size_t)d * 256 + bj + tx * 8) = *(float4*)&acc[i][0];
    *(float4*)(C + (size_t)d * 256 + bj + tx * 8 + 4) = *(float4*)&acc[i][4];
  }
}

// Panel kb: factor diag, invert -> write W (invD, fp32, upper zeros) over diag,
// TRSM sub-panel, write L to lower and L^T to upper (kb,i).
__global__ __launch_bounds__(256) void k_panel(float* __restrict__ L, int kb) {
  extern __shared__ float lds[];
  float* P = lds;
  float* W = lds + 64 * 68;
  float* WT = lds + 2 * 64 * 68;
  float* T = lds + 3 * 64 * 68;
  int s = blockIdx.x;
  float* M = L + (size_t)s * 65536;
  int tid = threadIdx.x;
  int k4 = tid & 15, rb = tid >> 4;
  int ty = tid >> 4, tx = tid & 15;
  int base = kb * 64;

  for (int r = rb; r < 64; r += 16)
    *(float4*)&P[r * 68 + k4 * 4] = *(const float4*)(M + (size_t)(base + r) * 256 + base + k4 * 4);
  __syncthreads();
  for (int c = 0; c < 64; ++c) {
    if (tid == 0) P[c * 68 + c] = sqrtf(P[c * 68 + c]);
    __syncthreads();
    float dinv = 1.0f / P[c * 68 + c];
    int r = c + 1 + tid;
    if (r < 64) P[r * 68 + c] *= dinv;
    __syncthreads();
    int eo = tid & 63, ro = tid >> 6;
    int e = c + 1 + eo;
    if (e < 64) {
      float le = P[e * 68 + c];
      for (int r2 = c + 1 + ro; r2 < 64; r2 += 4) P[r2 * 68 + e] -= P[r2 * 68 + c] * le;
    }
    __syncthreads();
  }
  if (tid < 64) {
    int c = tid;
    for (int r = 0; r < c; ++r) W[r * 68 + c] = 0.f;
    W[c * 68 + c] = 1.0f / P[c * 68 + c];
    for (int r = c + 1; r < 64; ++r) {
      float a = 0.f;
      for (int k = c; k < r; ++k) a += P[r * 68 + k] * W[k * 68 + c];
      W[r * 68 + c] = -a / P[r * 68 + r];
    }
  }
  __syncthreads();
  // WT for the TRSM GEMM (b-operand wants invD^T k-major)
  for (int c = rb; c < 64; c += 16) {
    float4 v = *(float4*)&W[c * 68 + k4 * 4];
    WT[(k4 * 4 + 0) * 68 + c] = v.x;
    WT[(k4 * 4 + 1) * 68 + c] = v.y;
    WT[(k4 * 4 + 2) * 68 + c] = v.z;
    WT[(k4 * 4 + 3) * 68 + c] = v.w;
  }
  __syncthreads();
  // write W (untransposed invD) over diag block for k_inv
  for (int r = rb; r < 64; r += 16)
    *(float4*)(M + (size_t)(base + r) * 256 + base + k4 * 4) = *(float4*)&W[r * 68 + k4 * 4];
  int nrt = 3 - kb;
  for (int rt = 0; rt < nrt; ++rt) {
    int g0 = base + 64 + rt * 64;
    __syncthreads();
    for (int r = rb; r < 64; r += 16) {
      float4 v = *(const float4*)(M + (size_t)(g0 + r) * 256 + base + k4 * 4);
      T[(k4 * 4 + 0) * 68 + r] = v.x;
      T[(k4 * 4 + 1) * 68 + r] = v.y;
      T[(k4 * 4 + 2) * 68 + r] = v.z;
      T[(k4 * 4 + 3) * 68 + r] = v.w;
    }
    __syncthreads();
    float acc[4][4] = {};
    for (int k = 0; k < 64; ++k) {
      float a[4], b[4];
      *(float4*)a = *(float4*)&T[k * 68 + ty * 4];
      *(float4*)b = *(float4*)&WT[k * 68 + tx * 4];
#pragma unroll
      for (int i = 0; i < 4; ++i)
#pragma unroll
        for (int j = 0; j < 4; ++j) acc[i][j] += a[i] * b[j];
    }
    __syncthreads();
#pragma unroll
    for (int i = 0; i < 4; ++i)
      *(float4*)(M + (size_t)(g0 + ty * 4 + i) * 256 + base + tx * 4) =
          make_float4(acc[i][0], acc[i][1], acc[i][2], acc[i][3]);
#pragma unroll
    for (int i = 0; i < 4; ++i)
#pragma unroll
      for (int j = 0; j < 4; ++j) T[(tx * 4 + j) * 68 + ty * 4 + i] = acc[i][j];
    __syncthreads();
    for (int r = rb; r < 64; r += 16)
      *(float4*)(M + (size_t)(base + r) * 256 + g0 + k4 * 4) = *(float4*)&T[r * 68 + k4 * 4];
  }
}

// Trailing update: C(ti,tj) -= L_i L_j^T.
__global__ __launch_bounds__(256) void k_trail(float* __restrict__ L, int kb) {
  extern __shared__ float lds[];
  float* Pi = lds;
  float* Pj = lds + 64 * 68;
  int p = blockIdx.x, s = blockIdx.y;
  int ti = 0, tj = 0, cnt = 0;
  for (int a = kb + 1; a < 4; ++a)
    for (int b = kb + 1; b <= a; ++b) {
      if (cnt == p) { ti = a; tj = b; }
      ++cnt;
    }
  float* M = L + (size_t)s * 65536;
  int tid = threadIdx.x, k4 = tid & 15, rb = tid >> 4;
  int ty = tid >> 4, tx = tid & 15;
  int base = kb * 64;
  for (int k = rb; k < 64; k += 16) {
    *(float4*)&Pi[k * 68 + k4 * 4] = *(const float4*)(M + (size_t)(base + k) * 256 + ti * 64 + k4 * 4);
    *(float4*)&Pj[k * 68 + k4 * 4] = *(const float4*)(M + (size_t)(base + k) * 256 + tj * 64 + k4 * 4);
  }
  float acc[4][4];
#pragma unroll
  for (int i = 0; i < 4; ++i)
    *(float4*)&acc[i][0] = *(const float4*)(M + (size_t)(ti * 64 + ty * 4 + i) * 256 + tj * 64 + tx * 4);
  __syncthreads();
  for (int k = 0; k < 64; ++k) {
    float a[4], b[4];
    *(float4*)a = *(float4*)&Pi[k * 68 + ty * 4];
    *(float4*)b = *(float4*)&Pj[k * 68 + tx * 4];
#pragma unroll
    for (int i = 0; i < 4; ++i)
#pragma unroll
      for (int j = 0; j < 4; ++j) acc[i][j] -= a[i] * b[j];
  }
#pragma unroll
  for (int i = 0; i < 4; ++i)
    *(float4*)(M + (size_t)(ti * 64 + ty * 4 + i) * 256 + tj * 64 + tx * 4) =
        make_float4(acc[i][0], acc[i][1], acc[i][2], acc[i][3]);
}

// invL per s, blockwise: B(j,j)=W_j; B(i,j) = -W_i * sum_{kk=j..i-1} L(i,kk)*B(kk,j).
// All results packed (hi<<16|lo) over lower+diag blocks of M.
// dyn LDS: Bcol 4*64*68 + Lt + Wt + Cs = 121,856 B
__global__ __launch_bounds__(256) void k_inv(float* __restrict__ Lw) {
  extern __shared__ float lds[];
  float* Bcol = lds;
  float* Lt = lds + 4 * 64 * 68;
  float* Wt = Lt + 64 * 68;
  float* Cs = Wt + 64 * 68;
  int s = blockIdx.x;
  float* M = Lw + (size_t)s * 65536;
  unsigned* M32 = (unsigned*)M;
  int tid = threadIdx.x, k4 = tid & 15, rb = tid >> 4;
  int ty = tid >> 4, tx = tid & 15;

  for (int j = 0; j < 4; ++j) {
    float* Bj = Bcol + j * 64 * 68;
    for (int r = rb; r < 64; r += 16) {
      float4 v = *(const float4*)(M + (size_t)(j * 64 + r) * 256 + j * 64 + k4 * 4);
      *(float4*)&Bj[r * 68 + k4 * 4] = v;
      uint4 pu;
      pu.x = packhl(v.x); pu.y = packhl(v.y); pu.z = packhl(v.z); pu.w = packhl(v.w);
      *(uint4*)(M32 + (size_t)(j * 64 + r) * 256 + j * 64 + k4 * 4) = pu;
    }
    for (int i = j + 1; i < 4; ++i) {
      float acc[4][4] = {};
      for (int kk = j; kk < i; ++kk) {
        __syncthreads();
        for (int k = rb; k < 64; k += 16)
          *(float4*)&Lt[k * 68 + k4 * 4] =
              *(const float4*)(M + (size_t)(kk * 64 + k) * 256 + i * 64 + k4 * 4);
        __syncthreads();
        float* Bk = Bcol + kk * 64 * 68;
        for (int k = 0; k < 64; ++k) {
          float a[4], b[4];
          *(float4*)a = *(float4*)&Lt[k * 68 + ty * 4];
          *(float4*)b = *(float4*)&Bk[k * 68 + tx * 4];
#pragma unroll
          for (int r = 0; r < 4; ++r)
#pragma unroll
            for (int c = 0; c < 4; ++c) acc[r][c] += a[r] * b[c];
        }
      }
      __syncthreads();
#pragma unroll
      for (int r = 0; r < 4; ++r)
        *(float4*)&Cs[(ty * 4 + r) * 68 + tx * 4] =
            make_float4(acc[r][0], acc[r][1], acc[r][2], acc[r][3]);
      for (int r = rb; r < 64; r += 16) {
        float4 v = *(const float4*)(M + (size_t)(i * 64 + r) * 256 + i * 64 + k4 * 4);
        Wt[(k4 * 4 + 0) * 68 + r] = v.x;
        Wt[(k4 * 4 + 1) * 68 + r] = v.y;
        Wt[(k4 * 4 + 2) * 68 + r] = v.z;
        Wt[(k4 * 4 + 3) * 68 + r] = v.w;
      }
      __syncthreads();
      float d[4][4] = {};
      for (int k = 0; k < 64; ++k) {
        float a[4], b[4];
        *(float4*)a = *(float4*)&Wt[k * 68 + ty * 4];
        *(float4*)b = *(float4*)&Cs[k * 68 + tx * 4];
#pragma unroll
        for (int r = 0; r < 4; ++r)
#pragma unroll
          for (int c = 0; c < 4; ++c) d[r][c] -= a[r] * b[c];
      }
      float* Bi = Bcol + i * 64 * 68;
#pragma unroll
      for (int r = 0; r < 4; ++r) {
        *(float4*)&Bi[(ty * 4 + r) * 68 + tx * 4] =
            make_float4(d[r][0], d[r][1], d[r][2], d[r][3]);
        uint4 pu;
        pu.x = packhl(d[r][0]); pu.y = packhl(d[r][1]);
        pu.z = packhl(d[r][2]); pu.w = packhl(d[r][3]);
        *(uint4*)(M32 + (size_t)(i * 64 + ty * 4 + r) * 256 + j * 64 + tx * 4) = pu;
      }
    }
    __syncthreads();
  }
}

// maha: y = invL * diff via MFMA split-3; maha = sum_d y^2 per b; + logdet + out.
// Grid (16 b-tiles, 256 s), 4 waves; wave w covers b columns b0+w*16+(0..15).
__global__ __launch_bounds__(256) void k_maha(const float* __restrict__ x,
                                              const float* __restrict__ mu_p,
                                              const float* __restrict__ Lw,
                                              float* __restrict__ out) {
  __shared__ float Red[65];
  int s = blockIdx.y, b0 = blockIdx.x * 64;
  const unsigned* M32 = (const unsigned*)(Lw + (size_t)s * 65536);
  int tid = threadIdx.x;
  int w = tid >> 6, lane = tid & 63;
  int q = lane >> 4, n = lane & 15;
  int b = b0 + w * 16 + n;
  // B cache: diff in bf16 hi/lo fragments, 8 k-steps of 32
  bf16x8 Bh[8], Bl[8];
  const float* xr = x + (size_t)b * 256 + q * 8;
  const float* mr = mu_p + (size_t)s * 256 + q * 8;
#pragma unroll
  for (int ks = 0; ks < 8; ++ks) {
    float4 xa = *(const float4*)(xr + ks * 32);
    float4 xb = *(const float4*)(xr + ks * 32 + 4);
    float4 ma = *(const float4*)(mr + ks * 32);
    float4 mb = *(const float4*)(mr + ks * 32 + 4);
    float dv[8] = {xa.x - ma.x, xa.y - ma.y, xa.z - ma.z, xa.w - ma.w,
                   xb.x - mb.x, xb.y - mb.y, xb.z - mb.z, xb.w - mb.w};
#pragma unroll
    for (int j = 0; j < 8; ++j) {
      unsigned h = bf16rtn(dv[j]);
      float hf = __uint_as_float(h << 16);
      unsigned l = bf16rtn(dv[j] - hf);
      Bh[ks][j] = (short)h;
      Bl[ks][j] = (short)l;
    }
  }
  float msum = 0.f;
#pragma unroll
  for (int mt = 0; mt < 16; ++mt) {
    f32x4 acc = {0.f, 0.f, 0.f, 0.f};
    const int nks = (mt + 2) >> 1;  // k < (mt+1)*16, zeros pad the rest
#pragma unroll
    for (int ks = 0; ks < nks; ++ks) {
      const unsigned* ap = M32 + (size_t)(mt * 16 + n) * 256 + ks * 32 + q * 8;
      uint4 u0 = *(const uint4*)ap;
      uint4 u1 = *(const uint4*)(ap + 4);
      unsigned uu[8] = {u0.x, u0.y, u0.z, u0.w, u1.x, u1.y, u1.z, u1.w};
      bf16x8 Ah, Al;
#pragma unroll
      for (int j = 0; j < 8; ++j) {
        Ah[j] = (short)(uu[j] >> 16);
        Al[j] = (short)(uu[j] & 0xffffu);
      }
      acc = __builtin_amdgcn_mfma_f32_16x16x32_bf16(Ah, Bh[ks], acc, 0, 0, 0);
      acc = __builtin_amdgcn_mfma_f32_16x16x32_bf16(Ah, Bl[ks], acc, 0, 0, 0);
      acc = __builtin_amdgcn_mfma_f32_16x16x32_bf16(Al, Bh[ks], acc, 0, 0, 0);
    }
    msum += acc[0] * acc[0] + acc[1] * acc[1] + acc[2] * acc[2] + acc[3] * acc[3];
  }
  msum += __shfl_xor(msum, 16, 64);
  msum += __shfl_xor(msum, 32, 64);
  if (lane < 16) Red[w * 16 + lane] = msum;
  if (w == 0) {
    float ld = 0.f;
#pragma unroll
    for (int c = 0; c < 4; ++c) {
      unsigned u = M32[(size_t)(c * 64 + lane) * 256 + c * 64 + lane];
      float v = __uint_as_float(u & 0xffff0000u) + __uint_as_float(u << 16);
      ld += logf(v);  // log(1/L_kk)
    }
    ld += __shfl_down(ld, 32, 64);
    ld += __shfl_down(ld, 16, 64);
    ld += __shfl_down(ld, 8, 64);
    ld += __shfl_down(ld, 4, 64);
    ld += __shfl_down(ld, 2, 64);
    ld += __shfl_down(ld, 1, 64);
    if (lane == 0) Red[64] = ld;
  }
  __syncthreads();
  if (tid < 64)
    out[(size_t)(b0 + tid) * 256 + s] = -0.5f * (LOG2PI_D - 2.0f * Red[64] + Red[tid]);
}

extern "C" void kernel_launch(void* const* d_in, const int* in_sizes, int n_in,
                              void* d_out, int out_size, void* d_ws, size_t ws_size,
                              hipStream_t stream) {
  const float* x = (const float*)d_in[0];
  const float* mu = (const float*)d_in[1];
  const float* sp = (const float*)d_in[2];
  float* out = (float*)d_out;
  float* L = (float*)d_ws;

  const int panel_lds = 4 * 64 * 68 * 4;   // 69,632
  const int trail_lds = 2 * 64 * 68 * 4;   // 34,816
  const int inv_lds = 7 * 64 * 68 * 4;     // 121,856
  (void)hipFuncSetAttribute((const void*)k_panel,
                            hipFuncAttributeMaxDynamicSharedMemorySize, panel_lds);
  (void)hipFuncSetAttribute((const void*)k_trail,
                            hipFuncAttributeMaxDynamicSharedMemorySize, trail_lds);
  (void)hipFuncSetAttribute((const void*)k_inv,
                            hipFuncAttributeMaxDynamicSharedMemorySize, inv_lds);

  k_ridge<<<256, 256, 0, stream>>>(sp, L);
  k_gram<<<dim3(3, 256), 256, 0, stream>>>(sp, L);
  const int npairs[4] = {6, 3, 1, 0};
  for (int kb = 0; kb < 4; ++kb) {
    k_panel<<<256, 256, panel_lds, stream>>>(L, kb);
    if (npairs[kb])
      k_trail<<<dim3(npairs[kb], 256), 256, trail_lds, stream>>>(L, kb);
  }
  k_inv<<<256, 256, inv_lds, stream>>>(L);
  k_maha<<<dim3(16, 256), 256, 0, stream>>>(x, mu, L, out);
}

// Round 5
// 961.068 us; speedup vs baseline: 1.0581x; 1.0581x over previous
//
#include <hip/hip_runtime.h>
#include <math.h>

// B=1024, S=256, D=256 fp32.
// logp[b,s] = -0.5*(D*log2pi + logdet_s + ||L_s^{-1}(x_b-mu_s)||^2)
//
// ws: one 256x256 fp32 matrix M per s (64 MB). Lifecycle:
//   ridge -> M[128];  gram -> lower+diag = sigma
//   panel(kb): factor diag kb, write W=invD (fp32, upper zeros) OVER diag kb,
//              TRSM sub-panel: L blocks to lower AND L^T copies to upper (kb,i)
//   trail(kb): C(ti,tj) -= L_i L_j^T (reads upper copies, updates lower)
//   invcol(j): column j of invL blockwise; strictly-lower blocks (i,j) i>j
//              overwritten with PACKED uint32 = (bf16_hi<<16)|bf16_lo.
//              Diag blocks keep fp32 W = invD (maha splits them on the fly).
//   maha: y = invL*diff via mfma_f32_16x16x32_bf16 split-3, ks-outer with
//         diff staged in LDS bf16 h/l; maha = colnorm(y)^2; logdet from fp32 diag.

#define LOG2PI_D 470.4965290007924f  // 256*log(2*pi)

typedef __attribute__((ext_vector_type(8))) short bf16x8;
typedef __attribute__((ext_vector_type(4))) float f32x4;

__device__ __forceinline__ unsigned bf16rtn(float f) {
  unsigned u = __float_as_uint(f);
  return (u + 0x7FFFu + ((u >> 16) & 1u)) >> 16;
}
__device__ __forceinline__ unsigned packhl(float v) {
  unsigned h = bf16rtn(v);
  float hf = __uint_as_float(h << 16);
  unsigned l = bf16rtn(v - hf);
  return (h << 16) | l;
}

__global__ __launch_bounds__(256) void k_ridge(const float* __restrict__ sp,
                                               float* __restrict__ L) {
  int s = blockIdx.x;
  const float4* p = (const float4*)(sp + (size_t)s * 65536);
  float acc = 0.f;
#pragma unroll 4
  for (int it = 0; it < 64; ++it) {
    float4 v = p[threadIdx.x + it * 256];
    acc += v.x * v.x + v.y * v.y + v.z * v.z + v.w * v.w;
  }
  for (int off = 32; off > 0; off >>= 1) acc += __shfl_down(acc, off, 64);
  __shared__ float red[4];
  if ((threadIdx.x & 63) == 0) red[threadIdx.x >> 6] = acc;
  __syncthreads();
  if (threadIdx.x == 0) {
    float t = red[0] + red[1] + red[2] + red[3];
    L[(size_t)s * 65536 + 128] = 0.01f * t / 256.0f;
  }
}

// Gram: C = sp^T sp (+ridge diag). 128x128 lower blocks only.
__global__ __launch_bounds__(256) void k_gram(const float* __restrict__ sp,
                                              float* __restrict__ L) {
  const int pi_[3] = {0, 1, 1};
  const int pj_[3] = {0, 0, 1};
  int p = blockIdx.x, s = blockIdx.y;
  int bi = pi_[p] * 128, bj = pj_[p] * 128;
  const float* A = sp + (size_t)s * 65536;
  float* C = L + (size_t)s * 65536;
  __shared__ float As[32][132];
  __shared__ float Bs[32][132];
  float acc[8][8] = {};
  int ty = threadIdx.x / 16, tx = threadIdx.x % 16;
  int lc4 = threadIdx.x % 32, lrb = threadIdx.x / 32;
  float ridge = C[128];
  for (int k0 = 0; k0 < 256; k0 += 32) {
    __syncthreads();
#pragma unroll
    for (int pass = 0; pass < 4; ++pass) {
      int r = lrb + pass * 8;
      *(float4*)&As[r][lc4 * 4] = *(const float4*)(A + (size_t)(k0 + r) * 256 + bi + lc4 * 4);
      *(float4*)&Bs[r][lc4 * 4] = *(const float4*)(A + (size_t)(k0 + r) * 256 + bj + lc4 * 4);
    }
    __syncthreads();
#pragma unroll
    for (int kk = 0; kk < 32; ++kk) {
      float a[8], b[8];
      *(float4*)&a[0] = *(float4*)&As[kk][ty * 8];
      *(float4*)&a[4] = *(float4*)&As[kk][ty * 8 + 4];
      *(float4*)&b[0] = *(float4*)&Bs[kk][tx * 8];
      *(float4*)&b[4] = *(float4*)&Bs[kk][tx * 8 + 4];
#pragma unroll
      for (int i = 0; i < 8; ++i)
#pragma unroll
        for (int j = 0; j < 8; ++j) acc[i][j] += a[i] * b[j];
    }
  }
#pragma unroll
  for (int i = 0; i < 8; ++i) {
    int d = bi + ty * 8 + i;
#pragma unroll
    for (int j = 0; j < 8; ++j) {
      int e = bj + tx * 8 + j;
      if (d == e) acc[i][j] += ridge;
    }
    *(float4*)(C + (size_t)d * 256 + bj + tx * 8) = *(float4*)&acc[i][0];
    *(float4*)(C + (size_t)d * 256 + bj + tx * 8 + 4) = *(float4*)&acc[i][4];
  }
}

// Panel kb: factor diag, invert -> write W (invD, fp32, upper zeros) over diag,
// TRSM sub-panel, write L to lower and L^T to upper (kb,i).
__global__ __launch_bounds__(256) void k_panel(float* __restrict__ L, int kb) {
  extern __shared__ float lds[];
  float* P = lds;
  float* W = lds + 64 * 68;
  float* WT = lds + 2 * 64 * 68;
  float* T = lds + 3 * 64 * 68;
  int s = blockIdx.x;
  float* M = L + (size_t)s * 65536;
  int tid = threadIdx.x;
  int k4 = tid & 15, rb = tid >> 4;
  int ty = tid >> 4, tx = tid & 15;
  int base = kb * 64;

  for (int r = rb; r < 64; r += 16)
    *(float4*)&P[r * 68 + k4 * 4] = *(const float4*)(M + (size_t)(base + r) * 256 + base + k4 * 4);
  __syncthreads();
  for (int c = 0; c < 64; ++c) {
    if (tid == 0) P[c * 68 + c] = sqrtf(P[c * 68 + c]);
    __syncthreads();
    float dinv = 1.0f / P[c * 68 + c];
    int r = c + 1 + tid;
    if (r < 64) P[r * 68 + c] *= dinv;
    __syncthreads();
    int eo = tid & 63, ro = tid >> 6;
    int e = c + 1 + eo;
    if (e < 64) {
      float le = P[e * 68 + c];
      for (int r2 = c + 1 + ro; r2 < 64; r2 += 4) P[r2 * 68 + e] -= P[r2 * 68 + c] * le;
    }
    __syncthreads();
  }
  if (tid < 64) {
    int c = tid;
    for (int r = 0; r < c; ++r) W[r * 68 + c] = 0.f;
    W[c * 68 + c] = 1.0f / P[c * 68 + c];
    for (int r = c + 1; r < 64; ++r) {
      float a = 0.f;
      for (int k = c; k < r; ++k) a += P[r * 68 + k] * W[k * 68 + c];
      W[r * 68 + c] = -a / P[r * 68 + r];
    }
  }
  __syncthreads();
  for (int c = rb; c < 64; c += 16) {
    float4 v = *(float4*)&W[c * 68 + k4 * 4];
    WT[(k4 * 4 + 0) * 68 + c] = v.x;
    WT[(k4 * 4 + 1) * 68 + c] = v.y;
    WT[(k4 * 4 + 2) * 68 + c] = v.z;
    WT[(k4 * 4 + 3) * 68 + c] = v.w;
  }
  __syncthreads();
  for (int r = rb; r < 64; r += 16)
    *(float4*)(M + (size_t)(base + r) * 256 + base + k4 * 4) = *(float4*)&W[r * 68 + k4 * 4];
  int nrt = 3 - kb;
  for (int rt = 0; rt < nrt; ++rt) {
    int g0 = base + 64 + rt * 64;
    __syncthreads();
    for (int r = rb; r < 64; r += 16) {
      float4 v = *(const float4*)(M + (size_t)(g0 + r) * 256 + base + k4 * 4);
      T[(k4 * 4 + 0) * 68 + r] = v.x;
      T[(k4 * 4 + 1) * 68 + r] = v.y;
      T[(k4 * 4 + 2) * 68 + r] = v.z;
      T[(k4 * 4 + 3) * 68 + r] = v.w;
    }
    __syncthreads();
    float acc[4][4] = {};
    for (int k = 0; k < 64; ++k) {
      float a[4], b[4];
      *(float4*)a = *(float4*)&T[k * 68 + ty * 4];
      *(float4*)b = *(float4*)&WT[k * 68 + tx * 4];
#pragma unroll
      for (int i = 0; i < 4; ++i)
#pragma unroll
        for (int j = 0; j < 4; ++j) acc[i][j] += a[i] * b[j];
    }
    __syncthreads();
#pragma unroll
    for (int i = 0; i < 4; ++i)
      *(float4*)(M + (size_t)(g0 + ty * 4 + i) * 256 + base + tx * 4) =
          make_float4(acc[i][0], acc[i][1], acc[i][2], acc[i][3]);
#pragma unroll
    for (int i = 0; i < 4; ++i)
#pragma unroll
      for (int j = 0; j < 4; ++j) T[(tx * 4 + j) * 68 + ty * 4 + i] = acc[i][j];
    __syncthreads();
    for (int r = rb; r < 64; r += 16)
      *(float4*)(M + (size_t)(base + r) * 256 + g0 + k4 * 4) = *(float4*)&T[r * 68 + k4 * 4];
  }
}

// Trailing update: C(ti,tj) -= L_i L_j^T.
__global__ __launch_bounds__(256) void k_trail(float* __restrict__ L, int kb) {
  extern __shared__ float lds[];
  float* Pi = lds;
  float* Pj = lds + 64 * 68;
  int p = blockIdx.x, s = blockIdx.y;
  int ti = 0, tj = 0, cnt = 0;
  for (int a = kb + 1; a < 4; ++a)
    for (int b = kb + 1; b <= a; ++b) {
      if (cnt == p) { ti = a; tj = b; }
      ++cnt;
    }
  float* M = L + (size_t)s * 65536;
  int tid = threadIdx.x, k4 = tid & 15, rb = tid >> 4;
  int ty = tid >> 4, tx = tid & 15;
  int base = kb * 64;
  for (int k = rb; k < 64; k += 16) {
    *(float4*)&Pi[k * 68 + k4 * 4] = *(const float4*)(M + (size_t)(base + k) * 256 + ti * 64 + k4 * 4);
    *(float4*)&Pj[k * 68 + k4 * 4] = *(const float4*)(M + (size_t)(base + k) * 256 + tj * 64 + k4 * 4);
  }
  float acc[4][4];
#pragma unroll
  for (int i = 0; i < 4; ++i)
    *(float4*)&acc[i][0] = *(const float4*)(M + (size_t)(ti * 64 + ty * 4 + i) * 256 + tj * 64 + tx * 4);
  __syncthreads();
  for (int k = 0; k < 64; ++k) {
    float a[4], b[4];
    *(float4*)a = *(float4*)&Pi[k * 68 + ty * 4];
    *(float4*)b = *(float4*)&Pj[k * 68 + tx * 4];
#pragma unroll
    for (int i = 0; i < 4; ++i)
#pragma unroll
      for (int j = 0; j < 4; ++j) acc[i][j] -= a[i] * b[j];
  }
#pragma unroll
  for (int i = 0; i < 4; ++i)
    *(float4*)(M + (size_t)(ti * 64 + ty * 4 + i) * 256 + tj * 64 + tx * 4) =
        make_float4(acc[i][0], acc[i][1], acc[i][2], acc[i][3]);
}

// invL column j (j=0..2): B(i,j) = -W_i * sum_{kk=j..i-1} L(i,kk)*B(kk,j),
// B(j,j)=W_j. Packed uint32 written over strictly-lower blocks. Columns are
// independent -> grid (3, 256). dyn LDS: (3 Bcol + LW + Cs)*64*68*4 = 87,040 B
__global__ __launch_bounds__(256) void k_invcol(float* __restrict__ Lw) {
  extern __shared__ float lds[];
  float* Bcol = lds;               // 3 slots [64][68]
  float* LW = lds + 3 * 64 * 68;   // staging: L(i,kk)^T, then W_i^T
  float* Cs = LW + 64 * 68;        // C staging
  int j = blockIdx.x, s = blockIdx.y;
  float* M = Lw + (size_t)s * 65536;
  unsigned* M32 = (unsigned*)M;
  int tid = threadIdx.x, k4 = tid & 15, rb = tid >> 4;
  int ty = tid >> 4, tx = tid & 15;

  // Bcol[0] = W_j (fp32 direct copy from diag block j)
  for (int r = rb; r < 64; r += 16)
    *(float4*)&Bcol[r * 68 + k4 * 4] =
        *(const float4*)(M + (size_t)(j * 64 + r) * 256 + j * 64 + k4 * 4);
  __syncthreads();

  for (int i = j + 1; i < 4; ++i) {
    float acc[4][4] = {};
    for (int kk = j; kk < i; ++kk) {
      __syncthreads();  // protect LW from previous phase reads
      for (int k = rb; k < 64; k += 16)
        *(float4*)&LW[k * 68 + k4 * 4] =
            *(const float4*)(M + (size_t)(kk * 64 + k) * 256 + i * 64 + k4 * 4);
      __syncthreads();
      float* Bk = Bcol + (kk - j) * 64 * 68;
#pragma unroll 4
      for (int k = 0; k < 64; ++k) {
        float a[4], b[4];
        *(float4*)a = *(float4*)&LW[k * 68 + ty * 4];
        *(float4*)b = *(float4*)&Bk[k * 68 + tx * 4];
#pragma unroll
        for (int r = 0; r < 4; ++r)
#pragma unroll
          for (int c = 0; c < 4; ++c) acc[r][c] += a[r] * b[c];
      }
    }
    __syncthreads();
#pragma unroll
    for (int r = 0; r < 4; ++r)
      *(float4*)&Cs[(ty * 4 + r) * 68 + tx * 4] =
          make_float4(acc[r][0], acc[r][1], acc[r][2], acc[r][3]);
    // stage W_i^T into LW
    for (int r = rb; r < 64; r += 16) {
      float4 v = *(const float4*)(M + (size_t)(i * 64 + r) * 256 + i * 64 + k4 * 4);
      LW[(k4 * 4 + 0) * 68 + r] = v.x;
      LW[(k4 * 4 + 1) * 68 + r] = v.y;
      LW[(k4 * 4 + 2) * 68 + r] = v.z;
      LW[(k4 * 4 + 3) * 68 + r] = v.w;
    }
    __syncthreads();
    float d[4][4] = {};
#pragma unroll 4
    for (int k = 0; k < 64; ++k) {
      float a[4], b[4];
      *(float4*)a = *(float4*)&LW[k * 68 + ty * 4];
      *(float4*)b = *(float4*)&Cs[k * 68 + tx * 4];
#pragma unroll
      for (int r = 0; r < 4; ++r)
#pragma unroll
        for (int c = 0; c < 4; ++c) d[r][c] -= a[r] * b[c];
    }
    float* Bi = Bcol + (i - j) * 64 * 68;
#pragma unroll
    for (int r = 0; r < 4; ++r) {
      if (i < 3)
        *(float4*)&Bi[(ty * 4 + r) * 68 + tx * 4] =
            make_float4(d[r][0], d[r][1], d[r][2], d[r][3]);
      uint4 pu;
      pu.x = packhl(d[r][0]); pu.y = packhl(d[r][1]);
      pu.z = packhl(d[r][2]); pu.w = packhl(d[r][3]);
      *(uint4*)(M32 + (size_t)(i * 64 + ty * 4 + r) * 256 + j * 64 + tx * 4) = pu;
    }
    __syncthreads();
  }
}

// maha: y = invL * diff (MFMA split-3), ks-outer, diff bf16 h/l staged in LDS.
// Block: 128 b-cols x all 256 d-rows; 4 waves, wave w owns mt {w, w+4, w+8, w+12}.
__global__ __launch_bounds__(256) void k_maha(const float* __restrict__ x,
                                              const float* __restrict__ mu_p,
                                              const float* __restrict__ Lw,
                                              float* __restrict__ out) {
  __shared__ __align__(16) short Bh[128 * 40];  // row b: 32 bf16, stride 40 (80 B)
  __shared__ __align__(16) short Bl[128 * 40];
  __shared__ float Red[513];
  int s = blockIdx.y, b0 = blockIdx.x * 128;
  const float* Mf = Lw + (size_t)s * 65536;
  const unsigned* M32 = (const unsigned*)Mf;
  int tid = threadIdx.x, w = tid >> 6, lane = tid & 63;
  int q = lane >> 4, n = lane & 15;
  f32x4 acc[4][8] = {};  // [t][bsub]

  for (int ks = 0; ks < 8; ++ks) {
    __syncthreads();  // previous chunk's B reads complete
    {
      // each thread covers 16 elements: row b = tid>>1, half = tid&1
      int b = tid >> 1, half = tid & 1;
      const float* xp = x + (size_t)(b0 + b) * 256 + ks * 32 + half * 16;
      const float* mp = mu_p + (size_t)s * 256 + ks * 32 + half * 16;
      float dv[16];
#pragma unroll
      for (int j4 = 0; j4 < 4; ++j4) {
        float4 xv = ((const float4*)xp)[j4];
        float4 mv = ((const float4*)mp)[j4];
        dv[j4 * 4 + 0] = xv.x - mv.x;
        dv[j4 * 4 + 1] = xv.y - mv.y;
        dv[j4 * 4 + 2] = xv.z - mv.z;
        dv[j4 * 4 + 3] = xv.w - mv.w;
      }
      unsigned h[16], l[16];
#pragma unroll
      for (int jj = 0; jj < 16; ++jj) {
        h[jj] = bf16rtn(dv[jj]);
        float hf = __uint_as_float(h[jj] << 16);
        l[jj] = bf16rtn(dv[jj] - hf);
      }
      *(uint4*)&Bh[b * 40 + half * 16] =
          make_uint4(h[0] | (h[1] << 16), h[2] | (h[3] << 16),
                     h[4] | (h[5] << 16), h[6] | (h[7] << 16));
      *(uint4*)&Bh[b * 40 + half * 16 + 8] =
          make_uint4(h[8] | (h[9] << 16), h[10] | (h[11] << 16),
                     h[12] | (h[13] << 16), h[14] | (h[15] << 16));
      *(uint4*)&Bl[b * 40 + half * 16] =
          make_uint4(l[0] | (l[1] << 16), l[2] | (l[3] << 16),
                     l[4] | (l[5] << 16), l[6] | (l[7] << 16));
      *(uint4*)&Bl[b * 40 + half * 16 + 8] =
          make_uint4(l[8] | (l[9] << 16), l[10] | (l[11] << 16),
                     l[12] | (l[13] << 16), l[14] | (l[15] << 16));
    }
    __syncthreads();
    // A tiles for this ks: wave's active mt set
    bf16x8 Ah[4], Al[4];
    bool act[4];
#pragma unroll
    for (int t = 0; t < 4; ++t) {
      int mt = w + 4 * t;
      act[t] = ks < ((mt + 2) >> 1);
      if (act[t]) {
        const unsigned* ap = M32 + (size_t)(mt * 16 + n) * 256 + ks * 32 + q * 8;
        uint4 u0 = *(const uint4*)ap;
        uint4 u1 = *(const uint4*)(ap + 4);
        unsigned uu[8] = {u0.x, u0.y, u0.z, u0.w, u1.x, u1.y, u1.z, u1.w};
        if ((ks >> 1) == (mt >> 2)) {  // diag block: fp32 W, split on the fly
#pragma unroll
          for (int jj = 0; jj < 8; ++jj) {
            float f = __uint_as_float(uu[jj]);
            unsigned hh = bf16rtn(f);
            float hf = __uint_as_float(hh << 16);
            Ah[t][jj] = (short)hh;
            Al[t][jj] = (short)bf16rtn(f - hf);
          }
        } else {  // packed invL
#pragma unroll
          for (int jj = 0; jj < 8; ++jj) {
            Ah[t][jj] = (short)(uu[jj] >> 16);
            Al[t][jj] = (short)(uu[jj] & 0xffffu);
          }
        }
      }
    }
#pragma unroll
    for (int bsub = 0; bsub < 8; ++bsub) {
      bf16x8 bh = *(const bf16x8*)&Bh[(bsub * 16 + n) * 40 + q * 8];
      bf16x8 bl = *(const bf16x8*)&Bl[(bsub * 16 + n) * 40 + q * 8];
#pragma unroll
      for (int t = 0; t < 4; ++t) {
        if (act[t]) {
          acc[t][bsub] = __builtin_amdgcn_mfma_f32_16x16x32_bf16(Ah[t], bh, acc[t][bsub], 0, 0, 0);
          acc[t][bsub] = __builtin_amdgcn_mfma_f32_16x16x32_bf16(Ah[t], bl, acc[t][bsub], 0, 0, 0);
          acc[t][bsub] = __builtin_amdgcn_mfma_f32_16x16x32_bf16(Al[t], bh, acc[t][bsub], 0, 0, 0);
        }
      }
    }
  }
  // reduce: per (bsub): sum over t, reg, then q -> column sums
#pragma unroll
  for (int bsub = 0; bsub < 8; ++bsub) {
    float v = 0.f;
#pragma unroll
    for (int t = 0; t < 4; ++t)
#pragma unroll
      for (int r = 0; r < 4; ++r) v += acc[t][bsub][r] * acc[t][bsub][r];
    v += __shfl_xor(v, 16, 64);
    v += __shfl_xor(v, 32, 64);
    if (lane < 16) Red[w * 128 + bsub * 16 + lane] = v;
  }
  if (w == 0) {
    float ld = 0.f;
#pragma unroll
    for (int c = 0; c < 4; ++c)
      ld += logf(Mf[(size_t)(c * 64 + lane) * 256 + c * 64 + lane]);  // log(1/L_kk)
    ld += __shfl_down(ld, 32, 64);
    ld += __shfl_down(ld, 16, 64);
    ld += __shfl_down(ld, 8, 64);
    ld += __shfl_down(ld, 4, 64);
    ld += __shfl_down(ld, 2, 64);
    ld += __shfl_down(ld, 1, 64);
    if (lane == 0) Red[512] = ld;
  }
  __syncthreads();
  if (tid < 128) {
    float mh = Red[tid] + Red[128 + tid] + Red[256 + tid] + Red[384 + tid];
    out[(size_t)(b0 + tid) * 256 + s] = -0.5f * (LOG2PI_D - 2.0f * Red[512] + mh);
  }
}

extern "C" void kernel_launch(void* const* d_in, const int* in_sizes, int n_in,
                              void* d_out, int out_size, void* d_ws, size_t ws_size,
                              hipStream_t stream) {
  const float* x = (const float*)d_in[0];
  const float* mu = (const float*)d_in[1];
  const float* sp = (const float*)d_in[2];
  float* out = (float*)d_out;
  float* L = (float*)d_ws;

  const int panel_lds = 4 * 64 * 68 * 4;   // 69,632
  const int trail_lds = 2 * 64 * 68 * 4;   // 34,816
  const int invc_lds = 5 * 64 * 68 * 4;    // 87,040
  (void)hipFuncSetAttribute((const void*)k_panel,
                            hipFuncAttributeMaxDynamicSharedMemorySize, panel_lds);
  (void)hipFuncSetAttribute((const void*)k_trail,
                            hipFuncAttributeMaxDynamicSharedMemorySize, trail_lds);
  (void)hipFuncSetAttribute((const void*)k_invcol,
                            hipFuncAttributeMaxDynamicSharedMemorySize, invc_lds);

  k_ridge<<<256, 256, 0, stream>>>(sp, L);
  k_gram<<<dim3(3, 256), 256, 0, stream>>>(sp, L);
  const int npairs[4] = {6, 3, 1, 0};
  for (int kb = 0; kb < 4; ++kb) {
    k_panel<<<256, 256, panel_lds, stream>>>(L, kb);
    if (npairs[kb])
      k_trail<<<dim3(npairs[kb], 256), 256, trail_lds, stream>>>(L, kb);
  }
  k_invcol<<<dim3(3, 256), 256, invc_lds, stream>>>(L);
  k_maha<<<dim3(8, 256), 256, 0, stream>>>(x, mu, L, out);
}

// Round 6
// 847.203 us; speedup vs baseline: 1.2003x; 1.1344x over previous
//
#include <hip/hip_runtime.h>
#include <math.h>

// B=1024, S=256, D=256 fp32.
// logp[b,s] = -0.5*(D*log2pi + logdet_s + ||L_s^{-1}(x_b-mu_s)||^2)
//
// ws: one 256x256 fp32 matrix M per s (64 MB). Lifecycle:
//   ridge -> M[128];  gram (MFMA split-3) -> lower+diag = sigma
//   panel(kb): factor diag kb, write W=invD (fp32, upper zeros) OVER diag kb,
//              TRSM sub-panel: L blocks to lower AND L^T copies to upper (kb,i)
//   trail(kb): C(ti,tj) -= L_i L_j^T (reads upper copies, updates lower)
//   invcol(j): column j of invL; strictly-lower blocks packed (bf16h<<16)|bf16l
//   maha: y = invL*diff via mfma split-3; 512-thr blocks, wave w owns mt {w,15-w}

#define LOG2PI_D 470.4965290007924f  // 256*log(2*pi)

typedef __attribute__((ext_vector_type(8))) short bf16x8;
typedef __attribute__((ext_vector_type(4))) float f32x4;

__device__ __forceinline__ unsigned bf16rtn(float f) {
  unsigned u = __float_as_uint(f);
  return (u + 0x7FFFu + ((u >> 16) & 1u)) >> 16;
}
__device__ __forceinline__ unsigned packhl(float v) {
  unsigned h = bf16rtn(v);
  float hf = __uint_as_float(h << 16);
  unsigned l = bf16rtn(v - hf);
  return (h << 16) | l;
}
__device__ __forceinline__ void unpack8(unsigned u0, unsigned u1, unsigned u2, unsigned u3,
                                        unsigned u4, unsigned u5, unsigned u6, unsigned u7,
                                        bf16x8* h, bf16x8* l) {
  unsigned uu[8] = {u0, u1, u2, u3, u4, u5, u6, u7};
#pragma unroll
  for (int j = 0; j < 8; ++j) {
    (*h)[j] = (short)(uu[j] >> 16);
    (*l)[j] = (short)(uu[j] & 0xffffu);
  }
}

__global__ __launch_bounds__(256) void k_ridge(const float* __restrict__ sp,
                                               float* __restrict__ L) {
  int s = blockIdx.x;
  const float4* p = (const float4*)(sp + (size_t)s * 65536);
  float acc = 0.f;
#pragma unroll 4
  for (int it = 0; it < 64; ++it) {
    float4 v = p[threadIdx.x + it * 256];
    acc += v.x * v.x + v.y * v.y + v.z * v.z + v.w * v.w;
  }
  for (int off = 32; off > 0; off >>= 1) acc += __shfl_down(acc, off, 64);
  __shared__ float red[4];
  if ((threadIdx.x & 63) == 0) red[threadIdx.x >> 6] = acc;
  __syncthreads();
  if (threadIdx.x == 0) {
    float t = red[0] + red[1] + red[2] + red[3];
    L[(size_t)s * 65536 + 128] = 0.01f * t / 256.0f;
  }
}

// Gram via MFMA split-3: C = sp^T sp (+ridge diag), 128x128 lower blocks.
// sp panels staged transposed in LDS as packed (h<<16)|l uint32, [col][k] stride 33.
// Waves: w owns mt {2w, 2w+1}; triangular tile culling for diag blocks.
__global__ __launch_bounds__(256) void k_gram(const float* __restrict__ sp,
                                              float* __restrict__ L) {
  __shared__ unsigned TrA[128 * 33];
  __shared__ unsigned TrB[128 * 33];
  int p = blockIdx.x, s = blockIdx.y;
  int bi = (p ? 128 : 0), bj = (p == 2 ? 128 : 0);
  const float* A = sp + (size_t)s * 65536;
  float* C = L + (size_t)s * 65536;
  float ridge = C[128];
  int tid = threadIdx.x, w = tid >> 6, lane = tid & 63;
  int q = lane >> 4, n = lane & 15;
  int mt0 = 2 * w;
  f32x4 acc[2][8] = {};
  int sr = tid >> 3, sc0 = (tid & 7) * 4;  // staging: row 0..31, col base

  for (int ks = 0; ks < 8; ++ks) {
    __syncthreads();
#pragma unroll
    for (int pass = 0; pass < 4; ++pass) {
      int c = sc0 + pass * 32;
      float4 v = *(const float4*)(A + (size_t)(ks * 32 + sr) * 256 + bi + c);
      TrA[(c + 0) * 33 + sr] = packhl(v.x);
      TrA[(c + 1) * 33 + sr] = packhl(v.y);
      TrA[(c + 2) * 33 + sr] = packhl(v.z);
      TrA[(c + 3) * 33 + sr] = packhl(v.w);
      if (p == 1) {
        float4 u = *(const float4*)(A + (size_t)(ks * 32 + sr) * 256 + bj + c);
        TrB[(c + 0) * 33 + sr] = packhl(u.x);
        TrB[(c + 1) * 33 + sr] = packhl(u.y);
        TrB[(c + 2) * 33 + sr] = packhl(u.z);
        TrB[(c + 3) * 33 + sr] = packhl(u.w);
      }
    }
    __syncthreads();
    const unsigned* TB = (p == 1) ? TrB : TrA;
    // A frags for mt0, mt0+1
    bf16x8 Ah[2], Al[2];
#pragma unroll
    for (int t = 0; t < 2; ++t) {
      const unsigned* ap = &TrA[((mt0 + t) * 16 + n) * 33 + q * 8];
      uint4 a0 = *(const uint4*)ap;
      uint4 a1 = *(const uint4*)(ap + 4);
      unpack8(a0.x, a0.y, a0.z, a0.w, a1.x, a1.y, a1.z, a1.w, &Ah[t], &Al[t]);
    }
    int ntmax = (p == 1) ? 8 : (mt0 + 2);
    for (int nt = 0; nt < ntmax; ++nt) {
      const unsigned* bp = &TB[(nt * 16 + n) * 33 + q * 8];
      uint4 b0v = *(const uint4*)bp;
      uint4 b1v = *(const uint4*)(bp + 4);
      bf16x8 bh, bl;
      unpack8(b0v.x, b0v.y, b0v.z, b0v.w, b1v.x, b1v.y, b1v.z, b1v.w, &bh, &bl);
#pragma unroll
      for (int t = 0; t < 2; ++t) {
        if (p == 1 || nt <= mt0 + t) {
          acc[t][nt] = __builtin_amdgcn_mfma_f32_16x16x32_bf16(Ah[t], bh, acc[t][nt], 0, 0, 0);
          acc[t][nt] = __builtin_amdgcn_mfma_f32_16x16x32_bf16(Ah[t], bl, acc[t][nt], 0, 0, 0);
          acc[t][nt] = __builtin_amdgcn_mfma_f32_16x16x32_bf16(Al[t], bh, acc[t][nt], 0, 0, 0);
        }
      }
    }
  }
#pragma unroll
  for (int t = 0; t < 2; ++t) {
    int mt = mt0 + t;
    int ntlim = (p == 1) ? 8 : (mt + 1);
    for (int nt = 0; nt < ntlim; ++nt) {
      int e = bj + nt * 16 + n;
#pragma unroll
      for (int r = 0; r < 4; ++r) {
        int d = bi + mt * 16 + q * 4 + r;
        float v = acc[t][nt][r];
        if (d == e) v += ridge;
        C[(size_t)d * 256 + e] = v;
      }
    }
  }
}

// Panel kb: factor diag, invert -> write W (invD, fp32, upper zeros) over diag,
// TRSM sub-panel, write L to lower and L^T to upper (kb,i).
__global__ __launch_bounds__(256) void k_panel(float* __restrict__ L, int kb) {
  extern __shared__ float lds[];
  float* P = lds;
  float* W = lds + 64 * 68;
  float* WT = lds + 2 * 64 * 68;
  float* T = lds + 3 * 64 * 68;
  int s = blockIdx.x;
  float* M = L + (size_t)s * 65536;
  int tid = threadIdx.x;
  int k4 = tid & 15, rb = tid >> 4;
  int ty = tid >> 4, tx = tid & 15;
  int base = kb * 64;

  for (int r = rb; r < 64; r += 16)
    *(float4*)&P[r * 68 + k4 * 4] = *(const float4*)(M + (size_t)(base + r) * 256 + base + k4 * 4);
  __syncthreads();
  for (int c = 0; c < 64; ++c) {
    if (tid == 0) P[c * 68 + c] = sqrtf(P[c * 68 + c]);
    __syncthreads();
    float dinv = 1.0f / P[c * 68 + c];
    int r = c + 1 + tid;
    if (r < 64) P[r * 68 + c] *= dinv;
    __syncthreads();
    int eo = tid & 63, ro = tid >> 6;
    int e = c + 1 + eo;
    if (e < 64) {
      float le = P[e * 68 + c];
      for (int r2 = c + 1 + ro; r2 < 64; r2 += 4) P[r2 * 68 + e] -= P[r2 * 68 + c] * le;
    }
    __syncthreads();
  }
  if (tid < 64) {
    int c = tid;
    for (int r = 0; r < c; ++r) W[r * 68 + c] = 0.f;
    W[c * 68 + c] = 1.0f / P[c * 68 + c];
    for (int r = c + 1; r < 64; ++r) {
      float a = 0.f;
      for (int k = c; k < r; ++k) a += P[r * 68 + k] * W[k * 68 + c];
      W[r * 68 + c] = -a / P[r * 68 + r];
    }
  }
  __syncthreads();
  for (int c = rb; c < 64; c += 16) {
    float4 v = *(float4*)&W[c * 68 + k4 * 4];
    WT[(k4 * 4 + 0) * 68 + c] = v.x;
    WT[(k4 * 4 + 1) * 68 + c] = v.y;
    WT[(k4 * 4 + 2) * 68 + c] = v.z;
    WT[(k4 * 4 + 3) * 68 + c] = v.w;
  }
  __syncthreads();
  for (int r = rb; r < 64; r += 16)
    *(float4*)(M + (size_t)(base + r) * 256 + base + k4 * 4) = *(float4*)&W[r * 68 + k4 * 4];
  int nrt = 3 - kb;
  for (int rt = 0; rt < nrt; ++rt) {
    int g0 = base + 64 + rt * 64;
    __syncthreads();
    for (int r = rb; r < 64; r += 16) {
      float4 v = *(const float4*)(M + (size_t)(g0 + r) * 256 + base + k4 * 4);
      T[(k4 * 4 + 0) * 68 + r] = v.x;
      T[(k4 * 4 + 1) * 68 + r] = v.y;
      T[(k4 * 4 + 2) * 68 + r] = v.z;
      T[(k4 * 4 + 3) * 68 + r] = v.w;
    }
    __syncthreads();
    float acc[4][4] = {};
    for (int k = 0; k < 64; ++k) {
      float a[4], b[4];
      *(float4*)a = *(float4*)&T[k * 68 + ty * 4];
      *(float4*)b = *(float4*)&WT[k * 68 + tx * 4];
#pragma unroll
      for (int i = 0; i < 4; ++i)
#pragma unroll
        for (int j = 0; j < 4; ++j) acc[i][j] += a[i] * b[j];
    }
    __syncthreads();
#pragma unroll
    for (int i = 0; i < 4; ++i)
      *(float4*)(M + (size_t)(g0 + ty * 4 + i) * 256 + base + tx * 4) =
          make_float4(acc[i][0], acc[i][1], acc[i][2], acc[i][3]);
#pragma unroll
    for (int i = 0; i < 4; ++i)
#pragma unroll
      for (int j = 0; j < 4; ++j) T[(tx * 4 + j) * 68 + ty * 4 + i] = acc[i][j];
    __syncthreads();
    for (int r = rb; r < 64; r += 16)
      *(float4*)(M + (size_t)(base + r) * 256 + g0 + k4 * 4) = *(float4*)&T[r * 68 + k4 * 4];
  }
}

// Trailing update: C(ti,tj) -= L_i L_j^T.
__global__ __launch_bounds__(256) void k_trail(float* __restrict__ L, int kb) {
  extern __shared__ float lds[];
  float* Pi = lds;
  float* Pj = lds + 64 * 68;
  int p = blockIdx.x, s = blockIdx.y;
  int ti = 0, tj = 0, cnt = 0;
  for (int a = kb + 1; a < 4; ++a)
    for (int b = kb + 1; b <= a; ++b) {
      if (cnt == p) { ti = a; tj = b; }
      ++cnt;
    }
  float* M = L + (size_t)s * 65536;
  int tid = threadIdx.x, k4 = tid & 15, rb = tid >> 4;
  int ty = tid >> 4, tx = tid & 15;
  int base = kb * 64;
  for (int k = rb; k < 64; k += 16) {
    *(float4*)&Pi[k * 68 + k4 * 4] = *(const float4*)(M + (size_t)(base + k) * 256 + ti * 64 + k4 * 4);
    *(float4*)&Pj[k * 68 + k4 * 4] = *(const float4*)(M + (size_t)(base + k) * 256 + tj * 64 + k4 * 4);
  }
  float acc[4][4];
#pragma unroll
  for (int i = 0; i < 4; ++i)
    *(float4*)&acc[i][0] = *(const float4*)(M + (size_t)(ti * 64 + ty * 4 + i) * 256 + tj * 64 + tx * 4);
  __syncthreads();
  for (int k = 0; k < 64; ++k) {
    float a[4], b[4];
    *(float4*)a = *(float4*)&Pi[k * 68 + ty * 4];
    *(float4*)b = *(float4*)&Pj[k * 68 + tx * 4];
#pragma unroll
    for (int i = 0; i < 4; ++i)
#pragma unroll
      for (int j = 0; j < 4; ++j) acc[i][j] -= a[i] * b[j];
  }
#pragma unroll
  for (int i = 0; i < 4; ++i)
    *(float4*)(M + (size_t)(ti * 64 + ty * 4 + i) * 256 + tj * 64 + tx * 4) =
        make_float4(acc[i][0], acc[i][1], acc[i][2], acc[i][3]);
}

// invL column j (j=0..2). dyn LDS: (3 Bcol + LW + Cs)*64*68*4 = 87,040 B
__global__ __launch_bounds__(256) void k_invcol(float* __restrict__ Lw) {
  extern __shared__ float lds[];
  float* Bcol = lds;
  float* LW = lds + 3 * 64 * 68;
  float* Cs = LW + 64 * 68;
  int j = blockIdx.x, s = blockIdx.y;
  float* M = Lw + (size_t)s * 65536;
  unsigned* M32 = (unsigned*)M;
  int tid = threadIdx.x, k4 = tid & 15, rb = tid >> 4;
  int ty = tid >> 4, tx = tid & 15;

  for (int r = rb; r < 64; r += 16)
    *(float4*)&Bcol[r * 68 + k4 * 4] =
        *(const float4*)(M + (size_t)(j * 64 + r) * 256 + j * 64 + k4 * 4);
  __syncthreads();

  for (int i = j + 1; i < 4; ++i) {
    float acc[4][4] = {};
    for (int kk = j; kk < i; ++kk) {
      __syncthreads();
      for (int k = rb; k < 64; k += 16)
        *(float4*)&LW[k * 68 + k4 * 4] =
            *(const float4*)(M + (size_t)(kk * 64 + k) * 256 + i * 64 + k4 * 4);
      __syncthreads();
      float* Bk = Bcol + (kk - j) * 64 * 68;
#pragma unroll 4
      for (int k = 0; k < 64; ++k) {
        float a[4], b[4];
        *(float4*)a = *(float4*)&LW[k * 68 + ty * 4];
        *(float4*)b = *(float4*)&Bk[k * 68 + tx * 4];
#pragma unroll
        for (int r = 0; r < 4; ++r)
#pragma unroll
          for (int c = 0; c < 4; ++c) acc[r][c] += a[r] * b[c];
      }
    }
    __syncthreads();
#pragma unroll
    for (int r = 0; r < 4; ++r)
      *(float4*)&Cs[(ty * 4 + r) * 68 + tx * 4] =
          make_float4(acc[r][0], acc[r][1], acc[r][2], acc[r][3]);
    for (int r = rb; r < 64; r += 16) {
      float4 v = *(const float4*)(M + (size_t)(i * 64 + r) * 256 + i * 64 + k4 * 4);
      LW[(k4 * 4 + 0) * 68 + r] = v.x;
      LW[(k4 * 4 + 1) * 68 + r] = v.y;
      LW[(k4 * 4 + 2) * 68 + r] = v.z;
      LW[(k4 * 4 + 3) * 68 + r] = v.w;
    }
    __syncthreads();
    float d[4][4] = {};
#pragma unroll 4
    for (int k = 0; k < 64; ++k) {
      float a[4], b[4];
      *(float4*)a = *(float4*)&LW[k * 68 + ty * 4];
      *(float4*)b = *(float4*)&Cs[k * 68 + tx * 4];
#pragma unroll
      for (int r = 0; r < 4; ++r)
#pragma unroll
        for (int c = 0; c < 4; ++c) d[r][c] -= a[r] * b[c];
    }
    float* Bi = Bcol + (i - j) * 64 * 68;
#pragma unroll
    for (int r = 0; r < 4; ++r) {
      if (i < 3)
        *(float4*)&Bi[(ty * 4 + r) * 68 + tx * 4] =
            make_float4(d[r][0], d[r][1], d[r][2], d[r][3]);
      uint4 pu;
      pu.x = packhl(d[r][0]); pu.y = packhl(d[r][1]);
      pu.z = packhl(d[r][2]); pu.w = packhl(d[r][3]);
      *(uint4*)(M32 + (size_t)(i * 64 + ty * 4 + r) * 256 + j * 64 + tx * 4) = pu;
    }
    __syncthreads();
  }
}

// maha: y = invL * diff (MFMA split-3), ks-outer, diff bf16 h/l staged in LDS.
// 512 threads (8 waves): wave w owns mt {w, 15-w} (balanced) x 8 bsub.
__global__ __launch_bounds__(512) void k_maha(const float* __restrict__ x,
                                              const float* __restrict__ mu_p,
                                              const float* __restrict__ Lw,
                                              float* __restrict__ out) {
  __shared__ __align__(16) short Bh[128 * 40];  // row b: 32 bf16, stride 40
  __shared__ __align__(16) short Bl[128 * 40];
  __shared__ float Red[1025];
  int s = blockIdx.y, b0 = blockIdx.x * 128;
  const float* Mf = Lw + (size_t)s * 65536;
  const unsigned* M32 = (const unsigned*)Mf;
  int tid = threadIdx.x, w = tid >> 6, lane = tid & 63;
  int q = lane >> 4, n = lane & 15;
  int mt_[2] = {w, 15 - w};
  f32x4 acc[2][8] = {};

  for (int ks = 0; ks < 8; ++ks) {
    __syncthreads();
    {
      // 512 threads x 8 elements: b = tid>>2, k-offset (tid&3)*8
      int b = tid >> 2, q8 = tid & 3;
      const float* xp = x + (size_t)(b0 + b) * 256 + ks * 32 + q8 * 8;
      const float* mp = mu_p + (size_t)s * 256 + ks * 32 + q8 * 8;
      float4 xa = ((const float4*)xp)[0], xb = ((const float4*)xp)[1];
      float4 ma = ((const float4*)mp)[0], mb = ((const float4*)mp)[1];
      float dv[8] = {xa.x - ma.x, xa.y - ma.y, xa.z - ma.z, xa.w - ma.w,
                     xb.x - mb.x, xb.y - mb.y, xb.z - mb.z, xb.w - mb.w};
      unsigned h[8], l[8];
#pragma unroll
      for (int jj = 0; jj < 8; ++jj) {
        h[jj] = bf16rtn(dv[jj]);
        float hf = __uint_as_float(h[jj] << 16);
        l[jj] = bf16rtn(dv[jj] - hf);
      }
      *(uint4*)&Bh[b * 40 + q8 * 8] =
          make_uint4(h[0] | (h[1] << 16), h[2] | (h[3] << 16),
                     h[4] | (h[5] << 16), h[6] | (h[7] << 16));
      *(uint4*)&Bl[b * 40 + q8 * 8] =
          make_uint4(l[0] | (l[1] << 16), l[2] | (l[3] << 16),
                     l[4] | (l[5] << 16), l[6] | (l[7] << 16));
    }
    __syncthreads();
    bf16x8 Ah[2], Al[2];
    bool act[2];
#pragma unroll
    for (int t = 0; t < 2; ++t) {
      int mt = mt_[t];
      act[t] = ks < ((mt + 2) >> 1);
      if (act[t]) {
        const unsigned* ap = M32 + (size_t)(mt * 16 + n) * 256 + ks * 32 + q * 8;
        uint4 u0 = *(const uint4*)ap;
        uint4 u1 = *(const uint4*)(ap + 4);
        unsigned uu[8] = {u0.x, u0.y, u0.z, u0.w, u1.x, u1.y, u1.z, u1.w};
        if ((ks >> 1) == (mt >> 2)) {  // diag block: fp32 W, split on the fly
#pragma unroll
          for (int jj = 0; jj < 8; ++jj) {
            float f = __uint_as_float(uu[jj]);
            unsigned hh = bf16rtn(f);
            float hf = __uint_as_float(hh << 16);
            Ah[t][jj] = (short)hh;
            Al[t][jj] = (short)bf16rtn(f - hf);
          }
        } else {  // packed invL
#pragma unroll
          for (int jj = 0; jj < 8; ++jj) {
            Ah[t][jj] = (short)(uu[jj] >> 16);
            Al[t][jj] = (short)(uu[jj] & 0xffffu);
          }
        }
      }
    }
#pragma unroll
    for (int bsub = 0; bsub < 8; ++bsub) {
      bf16x8 bh = *(const bf16x8*)&Bh[(bsub * 16 + n) * 40 + q * 8];
      bf16x8 bl = *(const bf16x8*)&Bl[(bsub * 16 + n) * 40 + q * 8];
#pragma unroll
      for (int t = 0; t < 2; ++t) {
        if (act[t]) {
          acc[t][bsub] = __builtin_amdgcn_mfma_f32_16x16x32_bf16(Ah[t], bh, acc[t][bsub], 0, 0, 0);
          acc[t][bsub] = __builtin_amdgcn_mfma_f32_16x16x32_bf16(Ah[t], bl, acc[t][bsub], 0, 0, 0);
          acc[t][bsub] = __builtin_amdgcn_mfma_f32_16x16x32_bf16(Al[t], bh, acc[t][bsub], 0, 0, 0);
        }
      }
    }
  }
#pragma unroll
  for (int bsub = 0; bsub < 8; ++bsub) {
    float v = 0.f;
#pragma unroll
    for (int t = 0; t < 2; ++t)
#pragma unroll
      for (int r = 0; r < 4; ++r) v += acc[t][bsub][r] * acc[t][bsub][r];
    v += __shfl_xor(v, 16, 64);
    v += __shfl_xor(v, 32, 64);
    if (lane < 16) Red[w * 128 + bsub * 16 + lane] = v;
  }
  if (w == 0) {
    float ld = 0.f;
#pragma unroll
    for (int c = 0; c < 4; ++c)
      ld += logf(Mf[(size_t)(c * 64 + lane) * 256 + c * 64 + lane]);  // log(1/L_kk)
    ld += __shfl_down(ld, 32, 64);
    ld += __shfl_down(ld, 16, 64);
    ld += __shfl_down(ld, 8, 64);
    ld += __shfl_down(ld, 4, 64);
    ld += __shfl_down(ld, 2, 64);
    ld += __shfl_down(ld, 1, 64);
    if (lane == 0) Red[1024] = ld;
  }
  __syncthreads();
  if (tid < 128) {
    float mh = 0.f;
#pragma unroll
    for (int w2 = 0; w2 < 8; ++w2) mh += Red[w2 * 128 + tid];
    out[(size_t)(b0 + tid) * 256 + s] = -0.5f * (LOG2PI_D - 2.0f * Red[1024] + mh);
  }
}

extern "C" void kernel_launch(void* const* d_in, const int* in_sizes, int n_in,
                              void* d_out, int out_size, void* d_ws, size_t ws_size,
                              hipStream_t stream) {
  const float* x = (const float*)d_in[0];
  const float* mu = (const float*)d_in[1];
  const float* sp = (const float*)d_in[2];
  float* out = (float*)d_out;
  float* L = (float*)d_ws;

  const int panel_lds = 4 * 64 * 68 * 4;   // 69,632
  const int trail_lds = 2 * 64 * 68 * 4;   // 34,816
  const int invc_lds = 5 * 64 * 68 * 4;    // 87,040
  (void)hipFuncSetAttribute((const void*)k_panel,
                            hipFuncAttributeMaxDynamicSharedMemorySize, panel_lds);
  (void)hipFuncSetAttribute((const void*)k_trail,
                            hipFuncAttributeMaxDynamicSharedMemorySize, trail_lds);
  (void)hipFuncSetAttribute((const void*)k_invcol,
                            hipFuncAttributeMaxDynamicSharedMemorySize, invc_lds);

  k_ridge<<<256, 256, 0, stream>>>(sp, L);
  k_gram<<<dim3(3, 256), 256, 0, stream>>>(sp, L);
  const int npairs[4] = {6, 3, 1, 0};
  for (int kb = 0; kb < 4; ++kb) {
    k_panel<<<256, 256, panel_lds, stream>>>(L, kb);
    if (npairs[kb])
      k_trail<<<dim3(npairs[kb], 256), 256, trail_lds, stream>>>(L, kb);
  }
  k_invcol<<<dim3(3, 256), 256, invc_lds, stream>>>(L);
  k_maha<<<dim3(8, 256), 512, 0, stream>>>(x, mu, L, out);
}